// Round 7
// baseline (1263.883 us; speedup 1.0000x reference)
//
#include <hip/hip_runtime.h>

// LocallyConnected2d: x [64,32,64,64] f32, w [1,64,32,62,62,9] f32 -> out [64,64,62,62] f32
// out[b,o,loc] = sum_{i,k} x[b,i,oh+k/3,ow+k%3] * w[o,i,loc,k]
//
// Round-7: no LDS, no barriers, all-global. Per-thread C-tile [4 b][8 loc] at one o
// (acc = 32 VGPR). Weight = contiguous 72-float run per (o,i,loc0..7): 18 dwordx4
// into 72 VGPRs per channel, consumed via static component selects (zero VALU).
// x: 10 dwordx4 per r-section from xT (16 b-groups -> 256B coalesced, L1-hot across
// the block's 4 waves). Live ~160 regs <= 170 (launch_bounds(256,3), 3 waves/SIMD).
// sched_barrier(0) per r-section caps scheduler load-batching (round-6's AGPR-spill
// source). Round-6 failures fixed: AGPR spill (184 live > 128 alloc'd) and
// weight-LDS reads exceeding the FMA budget.

#define OWDIM 62
#define LOCS 3844
#define WSI 34596u      // 62*62*9 floats per (o,i)
#define XM 131072u      // 32*64*64 per-batch x elements

__device__ __forceinline__ float f4get(const float4 v, int j) {
    return j == 0 ? v.x : j == 1 ? v.y : j == 2 ? v.z : v.w;
}
__device__ __forceinline__ void fma4(float4& a, float s, const float4 x) {
    a.x = fmaf(s, x.x, a.x);
    a.y = fmaf(s, x.y, a.y);
    a.z = fmaf(s, x.z, a.z);
    a.w = fmaf(s, x.w, a.w);
}

__global__ void lc2d_transpose_x(const float* __restrict__ x, float* __restrict__ xT) {
    __shared__ float tile[64][65];
    const int m0 = blockIdx.x * 64;
    const int t = threadIdx.x;
    const int c = t & 63, q = t >> 6;
#pragma unroll
    for (int jj = 0; jj < 16; ++jj) {
        const int b = q * 16 + jj;
        tile[c][b] = x[(size_t)b * XM + (size_t)(m0 + c)];
    }
    __syncthreads();
#pragma unroll
    for (int jj = 0; jj < 16; ++jj) {
        const int m = q * 16 + jj;
        xT[(size_t)(m0 + m) * 64u + (size_t)c] = tile[m][c];
    }
}

// static select of weight element (l, k) from the 18-float4 run (l,k compile-time)
#define WGET(l, k) f4get(W[((l) * 9 + (k)) >> 2], ((l) * 9 + (k)) & 3)

__global__ __launch_bounds__(256, 3) void lc2d_main(const float* __restrict__ w,
                                                    const float* __restrict__ xT,
                                                    float* __restrict__ out) {
    // grid 1984 = 8 XCD chunks x 248; within a chunk: o-quarter fastest (shares x
    // rows through L1/L2), then ow-tile (adjacent weight runs merge in L2).
    const int bid = blockIdx.x;
    const int t = (bid & 7) * 248 + (bid >> 3);
    const int oq = t & 3;
    const int rest = t >> 2;             // 0..495
    const int oh = rest >> 3;
    const int t8 = rest & 7;
    const int ow0 = (t8 < 7) ? (t8 << 3) : 54;   // last tile overlaps: no guards
    const int loc0 = oh * OWDIM + ow0;

    const int lane = threadIdx.x & 63;
    const int wave = __builtin_amdgcn_readfirstlane((int)(threadIdx.x >> 6));
    const int bg = lane & 15;            // b-group: b = bg*4 + db, db 0..3
    const int og = lane >> 4;            // o within wave's quartet
    const int o = oq * 16 + wave * 4 + og;

    const float* wbase = w + (size_t)((o * 32) * (size_t)LOCS + loc0) * 9u;
    const float* xbase = xT + (size_t)(bg * 4);

    float4 acc[8];
#pragma unroll
    for (int l = 0; l < 8; ++l) acc[l] = make_float4(0.f, 0.f, 0.f, 0.f);

#pragma unroll 1
    for (int i = 0; i < 32; ++i) {
        // weight run for (o, i): 72 contiguous floats (4B-aligned dwordx4 is legal)
        const float* wr = wbase + (size_t)i * WSI;
        float4 W[18];
#pragma unroll
        for (int j = 0; j < 18; ++j) W[j] = *(const float4*)(wr + 4 * j);

#pragma unroll
        for (int r = 0; r < 3; ++r) {
            const float* xp = xbase + ((size_t)i * 4096u + (size_t)((oh + r) * 64 + ow0)) * 64u;
            float4 Xa[10];
#pragma unroll
            for (int m = 0; m < 10; ++m)
                Xa[m] = *(const float4*)(xp + (size_t)(m * 64));
#pragma unroll
            for (int m = 0; m < 10; ++m) {
#pragma unroll
                for (int cc = 0; cc < 3; ++cc) {
                    const int l = m - cc;            // loc' hit by col m at tap-col cc
                    if (l >= 0 && l < 8)
                        fma4(acc[l], WGET(l, r * 3 + cc), Xa[m]);
                }
            }
            // keep only this section's Xa live; stop cross-section load batching
            __builtin_amdgcn_sched_barrier(0);
        }
    }

    // stores: per (b,o) an 8-float loc run -> 4x float2 (loc0 even -> 8B aligned)
#pragma unroll
    for (int db = 0; db < 4; ++db) {
        float* po = out + (size_t)((bg * 4 + db) * 64 + o) * (size_t)LOCS + (size_t)loc0;
        *(float2*)(po + 0) = make_float2(f4get(acc[0], db), f4get(acc[1], db));
        *(float2*)(po + 2) = make_float2(f4get(acc[2], db), f4get(acc[3], db));
        *(float2*)(po + 4) = make_float2(f4get(acc[4], db), f4get(acc[5], db));
        *(float2*)(po + 6) = make_float2(f4get(acc[6], db), f4get(acc[7], db));
    }
}

extern "C" void kernel_launch(void* const* d_in, const int* in_sizes, int n_in,
                              void* d_out, int out_size, void* d_ws, size_t ws_size,
                              hipStream_t stream) {
    const float* x = (const float*)d_in[0];   // 64*32*64*64
    const float* w = (const float*)d_in[1];   // 1*64*32*62*62*9
    float* out = (float*)d_out;               // 64*64*62*62
    float* xT = (float*)d_ws;                 // 32 MiB scratch

    lc2d_transpose_x<<<dim3(XM / 64), dim3(256), 0, stream>>>(x, xT);
    lc2d_main<<<dim3(1984), dim3(256), 0, stream>>>(w, xT, out);
}